// Round 2
// baseline (767.968 us; speedup 1.0000x reference)
//
#include <hip/hip_runtime.h>

// ---------------------------------------------------------------------------
// GraphAggregator: fused  [states = xW_lin+b] * softmax(xW_gate+b, dim=1)  ->
// segment-mean by sorted batch -> mean @ W_fin + b_fin.
// bf16 MFMA for the two big GEMMs (fused: x read from HBM exactly once),
// softmax in registers + small LDS exchange, pooling via per-column atomics
// into d_out (used as the sums buffer), finalize in-place.
// NOTE: harness passes integer inputs as int32 (batch is const int*).
// ---------------------------------------------------------------------------

typedef __attribute__((ext_vector_type(8))) short bf16x8;
typedef __attribute__((ext_vector_type(4))) float f32x4;

__device__ __forceinline__ short f2bf(float f) {
  unsigned u = __float_as_uint(f);
  unsigned r = (u + 0x7FFFu + ((u >> 16) & 1u)) >> 16;   // RNE
  return (short)r;
}

__device__ __forceinline__ void glds16(short* ldst, const short* gsrc) {
  __builtin_amdgcn_global_load_lds(
      (const __attribute__((address_space(1))) void*)gsrc,
      (__attribute__((address_space(3))) void*)ldst,
      16, 0, 0);
}

// ---------------------------------------------------------------------------
// prep_w: fp32 W[k][n] (256x256) -> bf16 blob in MFMA B-fragment order:
//   blob[mat][ks][ct*64+lane][j] = W[ks*32 + (lane>>4)*8 + j][ct*16 + (lane&15)]
// mat 0 = W_gate, mat 1 = W_lin. One block per (mat, ks) slice.
// ---------------------------------------------------------------------------
__global__ __launch_bounds__(256) void prep_w(const float* __restrict__ Wg,
                                              const float* __restrict__ Wl,
                                              short* __restrict__ blob) {
  __shared__ __align__(16) float tile[32][260];
  const int b = blockIdx.x;
  const int mat = b >> 3, ks = b & 7;
  const float* W = mat ? Wl : Wg;
  const int tid = threadIdx.x;
  #pragma unroll
  for (int i = 0; i < 8; ++i) {
    int f4 = tid + i * 256;
    int kl = f4 >> 6;
    int c0 = (f4 & 63) * 4;
    f32x4 v = *(const f32x4*)&W[(ks * 32 + kl) * 256 + c0];
    tile[kl][c0 + 0] = v[0]; tile[kl][c0 + 1] = v[1];
    tile[kl][c0 + 2] = v[2]; tile[kl][c0 + 3] = v[3];
  }
  __syncthreads();
  #pragma unroll
  for (int i = 0; i < 4; ++i) {
    int chunk = tid + i * 256;           // ct*64 + lane
    int ln = chunk & 63;
    int n  = ((chunk >> 6) << 4) + (ln & 15);
    int k0 = (ln >> 4) * 8;
    bf16x8 o;
    #pragma unroll
    for (int j = 0; j < 8; ++j) o[j] = f2bf(tile[k0 + j][n]);
    *(bf16x8*)&blob[(size_t)(mat * 8 + ks) * 8192 + (size_t)chunk * 8] = o;
  }
}

// ---------------------------------------------------------------------------
// fused_main: 128 rows/block, 512 threads (8 waves).
// wave = (rg = wave>>2 : which 64-row half, ch = wave&3 : which 64-col group)
// each wave: 4 row-tiles x 4 col-tiles of 16x16, both matrices (z and s).
// ---------------------------------------------------------------------------
__global__ __launch_bounds__(512, 2) void
fused_main(const float* __restrict__ x,
           const int* __restrict__ batch,
           const float* __restrict__ b_lin,
           const float* __restrict__ b_gate,
           const short* __restrict__ blob,
           float* __restrict__ sums) {
  __shared__ __align__(16) short xs[2 * 4096];      // 2 x-slabs (ks dbuf), 16 KB
  __shared__ __align__(16) short wl[2 * 16384];     // 2 W bufs x 2 mats, 64 KB
  __shared__ __align__(16) float pmax[512];         // [row_local][ch]
  __shared__ __align__(16) float psum[512];
  __shared__ __align__(16) float pool[512];         // [rg][col]
  __shared__ int batch_l[128];

  const int tid  = threadIdx.x;
  const int lane = tid & 63;
  const int wave = tid >> 6;
  const int quad = lane >> 4;
  const int ln15 = lane & 15;
  const int rg   = wave >> 2;
  const int ch   = wave & 3;
  const long long row0 = (long long)blockIdx.x * 128;

  if (tid < 128) batch_l[tid] = batch[row0 + tid];

  // prologue: async W slices (ks=0, both mats) into wl buf 0 + x slab ks=0
  glds16(wl + tid * 8,         blob + tid * 8);
  glds16(wl + 4096 + tid * 8,  blob + 4096 + tid * 8);
  glds16(wl + 8192 + tid * 8,  blob + (size_t)8 * 8192 + tid * 8);
  glds16(wl + 12288 + tid * 8, blob + (size_t)8 * 8192 + 4096 + tid * 8);
  {
    const int rt = tid >> 6, m = tid & 15, q = (tid >> 4) & 3;
    const float* src = x + (row0 + rt * 16 + m) * 256 + q * 8;
    f32x4 a = __builtin_nontemporal_load((const f32x4*)src);
    f32x4 b = __builtin_nontemporal_load((const f32x4*)(src + 4));
    bf16x8 o;
    o[0] = f2bf(a[0]); o[1] = f2bf(a[1]); o[2] = f2bf(a[2]); o[3] = f2bf(a[3]);
    o[4] = f2bf(b[0]); o[5] = f2bf(b[1]); o[6] = f2bf(b[2]); o[7] = f2bf(b[3]);
    *(bf16x8*)&xs[(size_t)tid * 8] = o;
  }
  __syncthreads();

  f32x4 accz[4][4], accs[4][4];
  #pragma unroll
  for (int r = 0; r < 4; ++r)
    #pragma unroll
    for (int c = 0; c < 4; ++c) {
      accz[r][c] = (f32x4)(0.0f);
      accs[r][c] = (f32x4)(0.0f);
    }

  #pragma unroll
  for (int ks = 0; ks < 8; ++ks) {
    f32x4 nx0, nx1;
    if (ks < 7) {
      short* wb = wl + ((ks + 1) & 1) * 16384;
      const short* g0 = blob + (size_t)(ks + 1) * 8192;
      const short* g1 = blob + (size_t)(8 + ks + 1) * 8192;
      glds16(wb + tid * 8,         g0 + tid * 8);
      glds16(wb + 4096 + tid * 8,  g0 + 4096 + tid * 8);
      glds16(wb + 8192 + tid * 8,  g1 + tid * 8);
      glds16(wb + 12288 + tid * 8, g1 + 4096 + tid * 8);
      const int rt = tid >> 6, m = tid & 15, q = (tid >> 4) & 3;
      const float* src = x + (row0 + rt * 16 + m) * 256 + (ks + 1) * 32 + q * 8;
      nx0 = __builtin_nontemporal_load((const f32x4*)src);
      nx1 = __builtin_nontemporal_load((const f32x4*)(src + 4));
    }
    // compute ks from current buffers
    const short* xb = xs + (ks & 1) * 4096;
    const short* wb = wl + (ks & 1) * 16384;
    bf16x8 afr[4];
    #pragma unroll
    for (int r = 0; r < 4; ++r)
      afr[r] = *(const bf16x8*)(xb + ((rg * 4 + r) * 64 + lane) * 8);
    #pragma unroll
    for (int c = 0; c < 4; ++c) {
      bf16x8 bz = *(const bf16x8*)(wb + ((ch * 4 + c) * 64 + lane) * 8);
      bf16x8 bs = *(const bf16x8*)(wb + 8192 + ((ch * 4 + c) * 64 + lane) * 8);
      #pragma unroll
      for (int r = 0; r < 4; ++r) {
        accz[r][c] = __builtin_amdgcn_mfma_f32_16x16x32_bf16(afr[r], bz, accz[r][c], 0, 0, 0);
        accs[r][c] = __builtin_amdgcn_mfma_f32_16x16x32_bf16(afr[r], bs, accs[r][c], 0, 0, 0);
      }
    }
    if (ks < 7) {
      bf16x8 o;
      o[0] = f2bf(nx0[0]); o[1] = f2bf(nx0[1]); o[2] = f2bf(nx0[2]); o[3] = f2bf(nx0[3]);
      o[4] = f2bf(nx1[0]); o[5] = f2bf(nx1[1]); o[6] = f2bf(nx1[2]); o[7] = f2bf(nx1[3]);
      *(bf16x8*)&xs[(size_t)(((ks + 1) & 1) * 512 + tid) * 8] = o;
    }
    __syncthreads();
  }

  // biases
  float bg[4], blv[4];
  #pragma unroll
  for (int c = 0; c < 4; ++c) {
    bg[c]  = b_gate[ch * 64 + c * 16 + ln15];
    blv[c] = b_lin [ch * 64 + c * 16 + ln15];
  }
  #pragma unroll
  for (int r = 0; r < 4; ++r)
    #pragma unroll
    for (int c = 0; c < 4; ++c)
      #pragma unroll
      for (int e = 0; e < 4; ++e) accz[r][c][e] += bg[c];

  // softmax over 256 cols per row (cols split across the 4 ch-waves)
  #pragma unroll
  for (int r = 0; r < 4; ++r)
    #pragma unroll
    for (int e = 0; e < 4; ++e) {
      float v = accz[r][0][e];
      #pragma unroll
      for (int c = 1; c < 4; ++c) v = fmaxf(v, accz[r][c][e]);
      v = fmaxf(v, __shfl_xor(v, 1));
      v = fmaxf(v, __shfl_xor(v, 2));
      v = fmaxf(v, __shfl_xor(v, 4));
      v = fmaxf(v, __shfl_xor(v, 8));
      if (ln15 == 0) pmax[(rg * 64 + r * 16 + quad * 4 + e) * 4 + ch] = v;
    }
  __syncthreads();
  #pragma unroll
  for (int r = 0; r < 4; ++r)
    #pragma unroll
    for (int e = 0; e < 4; ++e) {
      const int rl = rg * 64 + r * 16 + quad * 4 + e;
      f32x4 v4 = *(const f32x4*)&pmax[rl * 4];
      float fm = fmaxf(fmaxf(v4[0], v4[1]), fmaxf(v4[2], v4[3]));
      float s = 0.0f;
      #pragma unroll
      for (int c = 0; c < 4; ++c) {
        float ex = __expf(accz[r][c][e] - fm);
        accz[r][c][e] = ex;
        s += ex;
      }
      s += __shfl_xor(s, 1);
      s += __shfl_xor(s, 2);
      s += __shfl_xor(s, 4);
      s += __shfl_xor(s, 8);
      if (ln15 == 0) psum[rl * 4 + ch] = s;
    }
  __syncthreads();
  #pragma unroll
  for (int r = 0; r < 4; ++r)
    #pragma unroll
    for (int e = 0; e < 4; ++e) {
      const int rl = rg * 64 + r * 16 + quad * 4 + e;
      f32x4 v4 = *(const f32x4*)&psum[rl * 4];
      float inv = 1.0f / (v4[0] + v4[1] + v4[2] + v4[3]);
      #pragma unroll
      for (int c = 0; c < 4; ++c)
        accs[r][c][e] = (accs[r][c][e] + blv[c]) * (accz[r][c][e] * inv);  // gated
    }

  // segment pooling: loop graphs present in this block (usually exactly one)
  const int b0 = batch_l[0], b1 = batch_l[127];
  for (int g = b0; g <= b1; ++g) {
    float cs[4];
    #pragma unroll
    for (int c = 0; c < 4; ++c) cs[c] = 0.0f;
    #pragma unroll
    for (int r = 0; r < 4; ++r)
      #pragma unroll
      for (int e = 0; e < 4; ++e) {
        const int rl = rg * 64 + r * 16 + quad * 4 + e;
        const float m = (batch_l[rl] == g) ? 1.0f : 0.0f;
        #pragma unroll
        for (int c = 0; c < 4; ++c) cs[c] += accs[r][c][e] * m;
      }
    #pragma unroll
    for (int c = 0; c < 4; ++c) {
      cs[c] += __shfl_xor(cs[c], 16);
      cs[c] += __shfl_xor(cs[c], 32);
    }
    if (quad == 0) {
      #pragma unroll
      for (int c = 0; c < 4; ++c) pool[rg * 256 + ch * 64 + c * 16 + ln15] = cs[c];
    }
    __syncthreads();
    if (tid < 256)
      atomicAdd(&sums[(size_t)g * 256 + tid], pool[tid] + pool[256 + tid]);
    __syncthreads();
  }
}

// ---------------------------------------------------------------------------
// finalize (in-place: io holds per-graph sums on entry, final output on exit):
//   count_g via binary search over sorted batch; mean = sums/max(count,1);
//   out_row_g = mean_row_g @ W_fin + b_fin
// ---------------------------------------------------------------------------
__device__ __forceinline__ int lbound(const int* a, int n, int v) {
  int lo = 0, hi = n;
  while (lo < hi) {
    int mid = (lo + hi) >> 1;
    if (a[mid] < v) lo = mid + 1; else hi = mid;
  }
  return lo;
}

__global__ __launch_bounds__(256) void finalize(float* io,
                                                const int* __restrict__ batch, int N,
                                                const float* __restrict__ W_fin,
                                                const float* __restrict__ b_fin) {
  __shared__ __align__(16) float mrow[256];
  __shared__ float s_inv;
  const int g = blockIdx.x, tid = threadIdx.x;
  if (tid == 0) {
    int cnt = lbound(batch, N, g + 1) - lbound(batch, N, g);
    s_inv = 1.0f / fmaxf((float)cnt, 1.0f);
  }
  __syncthreads();
  mrow[tid] = io[(size_t)g * 256 + tid] * s_inv;
  __syncthreads();
  float acc = b_fin[tid];
  #pragma unroll 8
  for (int k = 0; k < 256; ++k)
    acc = fmaf(mrow[k], W_fin[k * 256 + tid], acc);
  io[(size_t)g * 256 + tid] = acc;
}

// ---------------------------------------------------------------------------
extern "C" void kernel_launch(void* const* d_in, const int* in_sizes, int n_in,
                              void* d_out, int out_size, void* d_ws, size_t ws_size,
                              hipStream_t stream) {
  const float* x      = (const float*)d_in[0];
  // d_in[1] = edge_index: unused by the reference
  const int*   batch  = (const int*)d_in[2];     // harness passes integers as int32
  const float* W_lin  = (const float*)d_in[3];
  const float* b_lin  = (const float*)d_in[4];
  const float* W_gate = (const float*)d_in[5];
  const float* b_gate = (const float*)d_in[6];
  const float* W_fin  = (const float*)d_in[7];
  const float* b_fin  = (const float*)d_in[8];
  float* out = (float*)d_out;                    // doubles as the sums buffer
  const int N = in_sizes[2];                     // 400000

  short* blob = (short*)d_ws;                    // 256 KB bf16 weight blob

  hipMemsetAsync(out, 0, (size_t)out_size * sizeof(float), stream);
  prep_w<<<16, 256, 0, stream>>>(W_gate, W_lin, blob);
  fused_main<<<3125, 512, 0, stream>>>(x, batch, b_lin, b_gate,
                                       (const short*)blob, out);
  finalize<<<512, 256, 0, stream>>>(out, batch, N, W_fin, b_fin);
}